// Round 2
// baseline (464.168 us; speedup 1.0000x reference)
//
#include <hip/hip_runtime.h>
#include <math.h>

#define BB 512
#define TT 512
#define OO 64

// ---------------- Main kernel: conf streamed to global ws ----------------
// One block per batch. 256 threads = 64 tags (j) x 4 i-chunks (c) of 16.
// LDS: backpointers u8 (32 KB) + state ping-pong + p vector + tag path.
// Softmax denominator via factorization: sum_i exp(s_i+T_ij-mu)
//   = sum_i p_i * E_ij,  p_i = exp(s_i - mu), E = exp(T) precomputed.
__global__ __launch_bounds__(256, 4) void crf_fwd_kernel(
    const float* __restrict__ logits,   // [B][T][O]
    const float* __restrict__ trans,    // [O][O]
    const int*   __restrict__ seqlens,  // [B]
    float* __restrict__ out,            // [2][B][T]
    unsigned char* __restrict__ confw)  // [B][T][O] u8 scratch
{
    const int b   = blockIdx.x;
    const int tid = threadIdx.x;
    const int j   = tid >> 2;   // tag 0..63
    const int c   = tid & 3;    // i-chunk 0..3

    __shared__ unsigned char bpl[TT][OO];   // backpointers
    __shared__ float st[2][OO];             // state ping-pong
    __shared__ float pl[OO];                // p_i = exp(s_i - mu)
    __shared__ unsigned char tagl[TT];      // decoded tag path

    const int L = seqlens[b];
    const float* lg = logits + (size_t)b * TT * OO;
    unsigned char* cw = confw + (size_t)b * TT * OO;

    // transition column chunk + its exp (E matrix), in registers
    float trc[16], trcE[16];
    #pragma unroll
    for (int i2 = 0; i2 < 16; ++i2) {
        float tv = trans[(c * 16 + i2) * OO + j];
        trc[i2]  = tv;
        trcE[i2] = __expf(tv);
    }

    if (tid < OO) st[0][tid] = lg[tid];
    __syncthreads();

    int cur = 0;
    float xr = (c == 0 && L > 1) ? lg[OO + j] : 0.f;  // prefetch t=1 emission

    for (int t = 1; t < L; ++t) {
        // ---- interval A: max-plus (exact, same as round-1), p producer ----
        float x = xr;
        if (c == 0 && t + 1 < L) xr = lg[(t + 1) * OO + j];  // prefetch next

        const float4* stv = (const float4*)&st[cur][c * 16];
        float4 s0 = stv[0], s1 = stv[1], s2 = stv[2], s3 = stv[3];
        float v[16];
        v[0]=s0.x+trc[0];  v[1]=s0.y+trc[1];  v[2]=s0.z+trc[2];  v[3]=s0.w+trc[3];
        v[4]=s1.x+trc[4];  v[5]=s1.y+trc[5];  v[6]=s1.z+trc[6];  v[7]=s1.w+trc[7];
        v[8]=s2.x+trc[8];  v[9]=s2.y+trc[9];  v[10]=s2.z+trc[10];v[11]=s2.w+trc[11];
        v[12]=s3.x+trc[12];v[13]=s3.y+trc[13];v[14]=s3.z+trc[14];v[15]=s3.w+trc[15];

        float m = -1e30f; int idx = 0;
        #pragma unroll
        for (int i2 = 0; i2 < 16; ++i2)
            if (v[i2] > m) { m = v[i2]; idx = c * 16 + i2; }  // first-max
        #pragma unroll
        for (int d = 1; d <= 2; d <<= 1) {
            float mo = __shfl_xor(m, d);
            int   io = __shfl_xor(idx, d);
            if (mo > m || (mo == m && io < idx)) { m = mo; idx = io; }
        }

        float mu = st[cur][0];                 // uniform shift (spread <= ~15)
        if (tid < OO) pl[tid] = __expf(st[cur][tid] - mu);   // wave 0 produces p

        if (c == 0) {
            st[cur ^ 1][j] = x + m;
            bpl[t][j] = (unsigned char)idx;
        }
        __syncthreads();

        // ---- interval B: denominator matvec + confidence ----
        const float4* pv = (const float4*)&pl[c * 16];
        float4 p0 = pv[0], p1 = pv[1], p2 = pv[2], p3 = pv[3];
        float den =
            p0.x*trcE[0]  + p0.y*trcE[1]  + p0.z*trcE[2]  + p0.w*trcE[3] +
            p1.x*trcE[4]  + p1.y*trcE[5]  + p1.z*trcE[6]  + p1.w*trcE[7] +
            p2.x*trcE[8]  + p2.y*trcE[9]  + p2.z*trcE[10] + p2.w*trcE[11] +
            p3.x*trcE[12] + p3.y*trcE[13] + p3.z*trcE[14] + p3.w*trcE[15];
        den += __shfl_xor(den, 1);
        den += __shfl_xor(den, 2);

        if (c == 0) {
            float conf = __expf(m - mu) / den;
            conf = fminf(conf, 1.0f);
            cw[t * OO + j] = (unsigned char)(conf * 255.0f + 0.5f);
        }
        cur ^= 1;
        __syncthreads();
    }

    // ---- epilogue: final argmax + serial backtrack into tagl ----
    if (tid == 0) {
        float m = -1e30f; int idx = 0;
        for (int jj = 0; jj < OO; ++jj) {
            float vv = st[cur][jj];
            if (vv > m) { m = vv; idx = jj; }
        }
        float s = 0.f;
        for (int jj = 0; jj < OO; ++jj)
            s += __expf(st[cur][jj] - m);

        float* out_tags   = out + (size_t)b * TT;
        float* out_scores = out + (size_t)BB * TT + (size_t)b * TT;
        out_tags[L - 1]   = (float)idx;
        out_scores[L - 1] = 1.0f / s;

        int tag = idx;
        tagl[L - 1] = (unsigned char)idx;
        for (int t = L - 1; t >= 1; --t) {
            tag = bpl[t][tag];
            tagl[t - 1] = (unsigned char)tag;
        }
    }
    __syncthreads();

    // ---- parallel: tags + conf gather (L2-hot) + masked tail ----
    float* out_tags   = out + (size_t)b * TT;
    float* out_scores = out + (size_t)BB * TT + (size_t)b * TT;
    for (int pos = tid; pos < L - 1; pos += 256) {
        int tnext = pos + 1;                 // score[pos] = conf(step t=pos+1, tag_{pos+1})
        out_tags[pos]   = (float)tagl[pos];
        out_scores[pos] = (float)cw[tnext * OO + tagl[tnext]] * (1.0f / 255.0f);
    }
    for (int pos = L + tid; pos < TT; pos += 256) {
        out_tags[pos]   = 0.f;
        out_scores[pos] = 0.f;
    }
}

// ---------------- Fallback (round-1 kernel): conf in LDS ----------------
__global__ __launch_bounds__(256) void crf_decode_fallback(
    const float* __restrict__ logits,
    const float* __restrict__ trans,
    const int*   __restrict__ seqlens,
    float* __restrict__ out)
{
    const int b   = blockIdx.x;
    const int tid = threadIdx.x;
    const int j   = tid >> 2;
    const int c   = tid & 3;

    __shared__ unsigned char bpl[TT][OO];
    __shared__ unsigned char scl[TT][OO];
    __shared__ float st[2][OO];

    const int L = seqlens[b];
    const float* lg = logits + (size_t)b * TT * OO;

    float trc[16];
    #pragma unroll
    for (int i2 = 0; i2 < 16; ++i2)
        trc[i2] = trans[(c * 16 + i2) * OO + j];

    if (tid < OO) st[0][tid] = lg[tid];
    __syncthreads();

    int cur = 0;
    for (int t = 1; t < L; ++t) {
        float x = lg[t * OO + j];
        float v[16];
        float m = -1e30f;
        int   idx = 0;
        #pragma unroll
        for (int i2 = 0; i2 < 16; ++i2) {
            float val = st[cur][c * 16 + i2] + trc[i2];
            v[i2] = val;
            if (val > m) { m = val; idx = c * 16 + i2; }
        }
        #pragma unroll
        for (int d = 1; d <= 2; d <<= 1) {
            float mo = __shfl_xor(m, d);
            int   io = __shfl_xor(idx, d);
            if (mo > m || (mo == m && io < idx)) { m = mo; idx = io; }
        }
        float s = 0.f;
        #pragma unroll
        for (int i2 = 0; i2 < 16; ++i2)
            s += __expf(v[i2] - m);
        #pragma unroll
        for (int d = 1; d <= 2; d <<= 1)
            s += __shfl_xor(s, d);

        if (c == 0) {
            st[cur ^ 1][j] = x + m;
            bpl[t][j] = (unsigned char)idx;
            float conf = 1.0f / s;
            conf = fminf(conf, 1.0f);
            scl[t][j] = (unsigned char)(conf * 255.0f + 0.5f);
        }
        cur ^= 1;
        __syncthreads();
    }

    if (tid == 0) {
        float m = -1e30f; int idx = 0;
        for (int jj = 0; jj < OO; ++jj) {
            float vv = st[cur][jj];
            if (vv > m) { m = vv; idx = jj; }
        }
        float s = 0.f;
        for (int jj = 0; jj < OO; ++jj)
            s += __expf(st[cur][jj] - m);

        float* out_tags   = out + (size_t)b * TT;
        float* out_scores = out + (size_t)BB * TT + (size_t)b * TT;
        out_tags[L - 1]   = (float)idx;
        out_scores[L - 1] = 1.0f / s;

        int tag = idx;
        for (int t = L - 1; t >= 1; --t) {
            int ntag  = bpl[t][tag];
            float sc  = (float)scl[t][tag] * (1.0f / 255.0f);
            out_tags[t - 1]   = (float)ntag;
            out_scores[t - 1] = sc;
            tag = ntag;
        }
    }

    float* out_tags   = out + (size_t)b * TT;
    float* out_scores = out + (size_t)BB * TT + (size_t)b * TT;
    for (int p = L + tid; p < TT; p += 256) {
        out_tags[p]   = 0.f;
        out_scores[p] = 0.f;
    }
}

extern "C" void kernel_launch(void* const* d_in, const int* in_sizes, int n_in,
                              void* d_out, int out_size, void* d_ws, size_t ws_size,
                              hipStream_t stream) {
    const float* logits = (const float*)d_in[0];
    const float* trans  = (const float*)d_in[1];
    const int*   lens   = (const int*)d_in[2];
    float* out = (float*)d_out;

    const size_t need = (size_t)BB * TT * OO;  // 16.8 MB of u8 conf scratch
    if (ws_size >= need) {
        crf_fwd_kernel<<<BB, 256, 0, stream>>>(logits, trans, lens, out,
                                               (unsigned char*)d_ws);
    } else {
        crf_decode_fallback<<<BB, 256, 0, stream>>>(logits, trans, lens, out);
    }
}